// Round 7
// baseline (1713.466 us; speedup 1.0000x reference)
//
#include <hip/hip_runtime.h>

#define NROWS 50000
#define DIM   256
#define SHOPS 6
#define ROUNDS 4
#define EPSV  1e-5f
#define ND ((size_t)NROWS * DIM)
#define NB  196                              // ceil(NROWS/256)

typedef _Float16 f16x8 __attribute__((ext_vector_type(8)));
typedef _Float16 f16x4 __attribute__((ext_vector_type(4)));
typedef float    f32x4 __attribute__((ext_vector_type(4)));

#define GLDS16(GP, LP) \
    __builtin_amdgcn_global_load_lds((const __attribute__((address_space(1))) unsigned*)(GP), \
                                     (__attribute__((address_space(3))) unsigned*)(LP), 16, 0, 0)

__device__ __forceinline__ int imin(int a, int b) { return a < b ? a : b; }

// ---------------------------------------------------------------------------
// Pipelined fp16 MFMA GEMM: C[z] = A @ W[base_slot+z]^T.
// Round-6 structure (XCD-chunked bijective swizzle, 3-buf counted-vmcnt
// pipeline, 64B-row XOR swizzle). ONE change: epilogue stores are
// NONTEMPORAL (stream past L2 write-allocate; Y is write-once-read-once).
// ---------------------------------------------------------------------------
__global__ __launch_bounds__(256)
void gemm_p(const _Float16* __restrict__ A, const _Float16* __restrict__ WH,
            int base_slot, int nz, _Float16* __restrict__ C16, int nwg)
{
    __shared__ _Float16 lds[3][8192];        // 3 x (A 8KB + W 8KB) = 48KB
    char* ldsb = (char*)lds;

    // bijective XCD chunking: consecutive g on same XCD; g is bx-major.
    const int bid = blockIdx.x;
    const int q   = nwg >> 3, r = nwg & 7;
    const int xcd = bid & 7,  ii = bid >> 3;
    const int g   = (xcd < r) ? xcd * (q + 1) + ii
                              : r * (q + 1) + (xcd - r) * q + ii;
    const int bx  = g / (2 * nz);
    const int sub = g - bx * 2 * nz;
    const int by  = sub & 1;
    const size_t z = sub >> 1;

    const int tid = threadIdx.x;
    const int l   = tid & 63;
    const int w   = tid >> 6;
    const int wm  = w & 1;
    const int wn  = w >> 1;
    const int bm0 = bx * 128;
    const int bn0 = by * 128;
    const int lr  = l & 15;
    const int sl  = l >> 4;                  // logical 16B k-slot 0..3

    const char* Ab = (const char*)A;
    const char* Wb = (const char*)(WH + (size_t)(base_slot + z) * (DIM * DIM));

    f32x4 acc[4][4];
    #pragma unroll
    for (int mt = 0; mt < 4; ++mt)
        #pragma unroll
        for (int nt = 0; nt < 4; ++nt)
            acc[mt][nt] = (f32x4){0.f, 0.f, 0.f, 0.f};

    // stage k-step `step` (32 k-elems = 64B per row) into buffer `buf`.
    auto stage = [&](int step, int buf) {
        const int kt64 = step * 64;
        char* base = ldsb + buf * 16384;
        #pragma unroll
        for (int qq = 0; qq < 2; ++qq) {
            const int c    = (w * 2 + qq) * 64 + l;   // 16B chunk 0..511
            const int row  = c >> 2;                  // 0..127
            const int slog = (c & 3) ^ ((row >> 1) & 3);
            const int ar   = imin(bm0 + row, NROWS - 1);
            GLDS16(Ab + (size_t)ar * 512 + kt64 + slog * 16,
                   base + (w * 2 + qq) * 1024);
            GLDS16(Wb + (size_t)(bn0 + row) * 512 + kt64 + slog * 16,
                   base + 8192 + (w * 2 + qq) * 1024);
        }
    };

    auto compute = [&](int buf) {
        const char* base = ldsb + buf * 16384;
        f16x8 af[4], bf[4];
        #pragma unroll
        for (int mt = 0; mt < 4; ++mt) {
            const int row = wm * 64 + mt * 16 + lr;
            af[mt] = *(const f16x8*)(base + row * 64 + ((sl ^ ((row >> 1) & 3)) << 4));
        }
        #pragma unroll
        for (int nt = 0; nt < 4; ++nt) {
            const int row = wn * 64 + nt * 16 + lr;
            bf[nt] = *(const f16x8*)(base + 8192 + row * 64 + ((sl ^ ((row >> 1) & 3)) << 4));
        }
        #pragma unroll
        for (int mt = 0; mt < 4; ++mt)
            #pragma unroll
            for (int nt = 0; nt < 4; ++nt)
                acc[mt][nt] = __builtin_amdgcn_mfma_f32_16x16x32_f16(
                    af[mt], bf[nt], acc[mt][nt], 0, 0, 0);
    };

    stage(0, 0);
    stage(1, 1);

    #pragma unroll
    for (int t = 0; t < 7; ++t) {
        asm volatile("s_waitcnt vmcnt(4)" ::: "memory");   // stage(t) landed
        __builtin_amdgcn_s_barrier();                       // all waves ready
        __builtin_amdgcn_sched_barrier(0);                  // pin order
        if (t < 6) stage(t + 2, (t + 2) % 3);               // stays in flight
        compute(t % 3);
    }
    asm volatile("s_waitcnt vmcnt(0)" ::: "memory");        // last stage
    __builtin_amdgcn_s_barrier();
    __builtin_amdgcn_sched_barrier(0);
    compute(7 % 3);

    // epilogue: same mapping as round 4/6, but NONTEMPORAL stores
    const int colb = bn0 + wn * 64 + lr;
    #pragma unroll
    for (int mt = 0; mt < 4; ++mt) {
        #pragma unroll
        for (int j = 0; j < 4; ++j) {
            const int row = bm0 + wm * 64 + mt * 16 + sl * 4 + j;
            if (row < NROWS) {
                #pragma unroll
                for (int nt = 0; nt < 4; ++nt)
                    __builtin_nontemporal_store(
                        (_Float16)acc[mt][nt][j],
                        C16 + z * ND + (size_t)row * DIM + colb + nt * 16);
            }
        }
    }
}

// ---------------------------------------------------------------------------
__global__ __launch_bounds__(256)
void convert_w(const float* __restrict__ Wctr, const float* __restrict__ Wctr2,
               const float* __restrict__ Wpre, const float* __restrict__ Wsuc,
               _Float16* __restrict__ WH)
{
    const size_t i4 = (size_t)blockIdx.x * 256 + threadIdx.x;
    const size_t NT = (size_t)56 * DIM * DIM / 4;
    if (i4 >= NT) return;
    const size_t e = i4 * 4;
    const int slot = (int)(e >> 16);
    const int off  = (int)(e & 65535);
    const float* src;
    if (slot < 48) {
        const int r = slot / 12, s = slot % 12, k = s >> 1, dir = s & 1;
        src = (dir ? Wsuc : Wpre) + (((size_t)r * SHOPS + k) << 16) + off;
    } else if (slot < 52) {
        src = Wctr + ((size_t)(slot - 48) << 16) + off;
    } else {
        src = Wctr2 + ((size_t)(slot - 52) << 16) + off;
    }
    const float4 v = *(const float4*)src;
    f16x4 h;
    h[0] = (_Float16)v.x; h[1] = (_Float16)v.y;
    h[2] = (_Float16)v.z; h[3] = (_Float16)v.w;
    *(f16x4*)(WH + e) = h;
}

__global__ __launch_bounds__(256)
void init_x(const float* __restrict__ lane, float* __restrict__ X,
            _Float16* __restrict__ Xh)
{
    const size_t i4 = (size_t)blockIdx.x * 256 + threadIdx.x;
    if (i4 >= ND / 4) return;
    const float4 v = *(const float4*)(lane + i4 * 4);
    *(float4*)(X + i4 * 4) = v;
    f16x4 h;
    h[0] = (_Float16)v.x; h[1] = (_Float16)v.y;
    h[2] = (_Float16)v.z; h[3] = (_Float16)v.w;
    *(f16x4*)(Xh + i4 * 4) = h;
}

// x = relu(gn(y)*w+b + res) -> X fp32 + Xh fp16
__global__ __launch_bounds__(256)
void gn1_kernel(const _Float16* __restrict__ inh, const float* __restrict__ w,
                const float* __restrict__ b, float* __restrict__ X,
                _Float16* __restrict__ Xh)
{
    const int lane = threadIdx.x & 63;
    const int wv   = threadIdx.x >> 6;
    const int row  = blockIdx.x * 4 + wv;
    if (row >= NROWS) return;

    const f16x4 hv = *(const f16x4*)(inh + (size_t)row * DIM + lane * 4);
    float4 v;
    v.x = (float)hv[0]; v.y = (float)hv[1]; v.z = (float)hv[2]; v.w = (float)hv[3];
    float s  = v.x + v.y + v.z + v.w;
    float ss = v.x * v.x + v.y * v.y + v.z * v.z + v.w * v.w;
    #pragma unroll
    for (int off = 32; off >= 1; off >>= 1) {
        s  += __shfl_xor(s, off);
        ss += __shfl_xor(ss, off);
    }
    const float m   = s * (1.0f / DIM);
    const float var = ss * (1.0f / DIM) - m * m;
    const float inv = rsqrtf(var + EPSV);

    const float4 wv4 = *(const float4*)(w + lane * 4);
    const float4 bv4 = *(const float4*)(b + lane * 4);
    const float4 r4  = *(const float4*)(X + (size_t)row * DIM + lane * 4);
    float4 o;
    o.x = fmaxf((v.x - m) * inv * wv4.x + bv4.x + r4.x, 0.f);
    o.y = fmaxf((v.y - m) * inv * wv4.y + bv4.y + r4.y, 0.f);
    o.z = fmaxf((v.z - m) * inv * wv4.z + bv4.z + r4.z, 0.f);
    o.w = fmaxf((v.w - m) * inv * wv4.w + bv4.w + r4.w, 0.f);
    *(float4*)(X + (size_t)row * DIM + lane * 4) = o;
    f16x4 oh;
    oh[0] = (_Float16)o.x; oh[1] = (_Float16)o.y;
    oh[2] = (_Float16)o.z; oh[3] = (_Float16)o.w;
    *(f16x4*)(Xh + (size_t)row * DIM + lane * 4) = oh;
}

// ---------------------------------------------------------------------------
// CSR inversion (once per launch; indices constant across rounds)
// ---------------------------------------------------------------------------
__global__ __launch_bounds__(256)
void count_kernel(const int* __restrict__ pidx, const int* __restrict__ sidx,
                  int* __restrict__ counts)
{
    const int i = blockIdx.x * 256 + threadIdx.x;
    if (i >= NROWS) return;
    const int s = blockIdx.y;
    const int k = s >> 1, dir = s & 1;
    const int* scp = (dir ? pidx : sidx) + k * NROWS;
    atomicAdd(&counts[scp[i]], 1);
}

__global__ __launch_bounds__(256)
void scan1_kernel(const int* __restrict__ counts, int* __restrict__ offs,
                  int* __restrict__ bsum)
{
    __shared__ int wsum[4];
    const int tid = threadIdx.x, lane = tid & 63, wv = tid >> 6;
    const int i = blockIdx.x * 256 + tid;
    const int c = (i < NROWS) ? counts[i] : 0;
    int v = c;
    #pragma unroll
    for (int off = 1; off < 64; off <<= 1) {
        const int t = __shfl_up(v, off);
        if (lane >= off) v += t;
    }
    if (lane == 63) wsum[wv] = v;
    __syncthreads();
    int add = 0;
    for (int w = 0; w < wv; ++w) add += wsum[w];
    if (i < NROWS) offs[i] = add + v - c;
    if (tid == 255) bsum[blockIdx.x] = wsum[0] + wsum[1] + wsum[2] + wsum[3];
}

__global__ __launch_bounds__(256)
void scan2_kernel(const int* __restrict__ bsum, int* __restrict__ bpre)
{
    __shared__ int wsum[4];
    const int tid = threadIdx.x, lane = tid & 63, wv = tid >> 6;
    const int c = (tid < NB) ? bsum[tid] : 0;
    int v = c;
    #pragma unroll
    for (int off = 1; off < 64; off <<= 1) {
        const int t = __shfl_up(v, off);
        if (lane >= off) v += t;
    }
    if (lane == 63) wsum[wv] = v;
    __syncthreads();
    int add = 0;
    for (int w = 0; w < wv; ++w) add += wsum[w];
    if (tid < NB) bpre[tid] = add + v - c;
}

__global__ __launch_bounds__(256)
void scan3_kernel(int* __restrict__ offs, const int* __restrict__ bpre,
                  int* __restrict__ cursor)
{
    const int i = blockIdx.x * 256 + threadIdx.x;
    if (i < NROWS) {
        const int v = offs[i] + bpre[blockIdx.x];
        offs[i] = v;
        cursor[i] = v;
    }
    if (i == 0) offs[NROWS] = 12 * NROWS;
}

__global__ __launch_bounds__(256)
void fill_kernel(const int* __restrict__ pidx, const int* __restrict__ sidx,
                 const int* __restrict__ nhp, const int* __restrict__ nhs,
                 int* __restrict__ cursor, int* __restrict__ entries)
{
    const int i = blockIdx.x * 256 + threadIdx.x;
    if (i >= NROWS) return;
    const int s = blockIdx.y;
    const int k = s >> 1, dir = s & 1;
    const int* scp = (dir ? pidx : sidx) + k * NROWS;
    const int* gp  = (dir ? nhs  : nhp)  + k * NROWS;
    const int pos = atomicAdd(&cursor[scp[i]], 1);
    entries[pos] = (s << 16) | gp[i];
}

// ---------------------------------------------------------------------------
// combine: acc = (FIRST ? YC[r] : TEMP16[r]) + sum of Y rows for entries with
// seg in [c0, c0+nch). Y reads NONTEMPORAL (dead after read; don't evict Xh).
// LAST: fused GroupNorm+ReLU -> Hh. else -> TEMP16.
// ---------------------------------------------------------------------------
template<int FIRST, int LAST>
__global__ __launch_bounds__(256)
void combine_f16(const _Float16* __restrict__ YC, _Float16* __restrict__ TEMP16,
                 const _Float16* __restrict__ YB,
                 const int* __restrict__ offsets, const int* __restrict__ entries,
                 int c0, int nch,
                 const float* __restrict__ gw, const float* __restrict__ gb,
                 _Float16* __restrict__ Hh)
{
    const int lane = threadIdx.x & 63;
    const int wv   = threadIdx.x >> 6;
    const int r    = blockIdx.x * 4 + wv;
    if (r >= NROWS) return;
    const size_t rowoff = (size_t)r * DIM + lane * 4;

    const f16x4 iv = FIRST ? __builtin_nontemporal_load((const f16x4*)(YC + rowoff))
                           : *(const f16x4*)(TEMP16 + rowoff);
    float4 acc;
    acc.x = (float)iv[0]; acc.y = (float)iv[1];
    acc.z = (float)iv[2]; acc.w = (float)iv[3];

    const int e0 = offsets[r], e1 = offsets[r + 1];
    for (int e = e0; e < e1; ++e) {
        const int ent = entries[e];
        const int s = ent >> 16;
        if ((unsigned)(s - c0) < (unsigned)nch) {
            const f16x4 yv = __builtin_nontemporal_load(
                (const f16x4*)(YB + (size_t)(s - c0) * ND
                               + (size_t)(ent & 0xFFFF) * DIM + lane * 4));
            acc.x += (float)yv[0]; acc.y += (float)yv[1];
            acc.z += (float)yv[2]; acc.w += (float)yv[3];
        }
    }

    if (LAST) {
        float s  = acc.x + acc.y + acc.z + acc.w;
        float ss = acc.x * acc.x + acc.y * acc.y + acc.z * acc.z + acc.w * acc.w;
        #pragma unroll
        for (int off = 32; off >= 1; off >>= 1) {
            s  += __shfl_xor(s, off);
            ss += __shfl_xor(ss, off);
        }
        const float m   = s * (1.0f / DIM);
        const float var = ss * (1.0f / DIM) - m * m;
        const float inv = rsqrtf(var + EPSV);
        const float4 wv4 = *(const float4*)(gw + lane * 4);
        const float4 bv4 = *(const float4*)(gb + lane * 4);
        f16x4 o;
        o[0] = (_Float16)fmaxf((acc.x - m) * inv * wv4.x + bv4.x, 0.f);
        o[1] = (_Float16)fmaxf((acc.y - m) * inv * wv4.y + bv4.y, 0.f);
        o[2] = (_Float16)fmaxf((acc.z - m) * inv * wv4.z + bv4.z, 0.f);
        o[3] = (_Float16)fmaxf((acc.w - m) * inv * wv4.w + bv4.w, 0.f);
        *(f16x4*)(Hh + rowoff) = o;
    } else {
        f16x4 o;
        o[0] = (_Float16)acc.x; o[1] = (_Float16)acc.y;
        o[2] = (_Float16)acc.z; o[3] = (_Float16)acc.w;
        *(f16x4*)(TEMP16 + rowoff) = o;
    }
}

// ---------------------------------------------------------------------------
extern "C" void kernel_launch(void* const* d_in, const int* in_sizes, int n_in,
                              void* d_out, int out_size, void* d_ws, size_t ws_size,
                              hipStream_t stream)
{
    const float* lane   = (const float*)d_in[0];
    const float* W_ctr  = (const float*)d_in[1];
    const float* norm_w = (const float*)d_in[2];
    const float* norm_b = (const float*)d_in[3];
    const float* W_ctr2 = (const float*)d_in[4];
    const float* c2w    = (const float*)d_in[5];
    const float* c2b    = (const float*)d_in[6];
    const float* W_pre  = (const float*)d_in[7];
    const float* W_suc  = (const float*)d_in[8];
    const int*   pidx   = (const int*)d_in[9];
    const int*   sidx   = (const int*)d_in[10];
    const int*   nhp    = (const int*)d_in[11];
    const int*   nhs    = (const int*)d_in[12];

    float* X = (float*)d_out;

    // ---- workspace layout ----
    char* p = (char*)d_ws;
    int* counts  = (int*)p; p += (size_t)NROWS * 4;
    int* offsets = (int*)p; p += (size_t)(NROWS + 4) * 4;
    int* cursor  = (int*)p; p += (size_t)NROWS * 4;
    int* bsum    = (int*)p; p += 256 * 4;
    int* bpre    = (int*)p; p += 256 * 4;
    int* entries = (int*)p; p += (size_t)12 * NROWS * 4;
    p = (char*)(((uintptr_t)p + 15) & ~(uintptr_t)15);
    _Float16* Xh   = (_Float16*)p; p += ND * 2;
    _Float16* Hh   = (_Float16*)p; p += ND * 2;
    _Float16* T16  = (_Float16*)p; p += ND * 2;
    _Float16* YC   = (_Float16*)p; p += ND * 2;
    _Float16* WH   = (_Float16*)p; p += (size_t)56 * DIM * DIM * 2;
    p = (char*)(((uintptr_t)p + 15) & ~(uintptr_t)15);
    _Float16* YBUF = (_Float16*)p;

    const size_t used = (size_t)(p - (char*)d_ws);
    int nslot = (int)((ws_size - used) / (ND * 2));
    if (nslot < 1) nslot = 1;
    int CH = nslot > 12 ? 12 : nslot;
    const int nchunks = (12 + CH - 1) / CH;
    CH = (12 + nchunks - 1) / nchunks;
    _Float16* Y2 = YBUF;   // ctr2 output reuses slot 0 (stream-ordered, safe)

    const dim3 blk(256);
    const int  gnBlocks = (NROWS + 3) / 4;
    const int  cwBlocks = (int)(((size_t)56 * DIM * DIM / 4 + 255) / 256);
    const int  ixBlocks = (int)((ND / 4 + 255) / 256);

    // one-time prep
    convert_w<<<cwBlocks, blk, 0, stream>>>(W_ctr, W_ctr2, W_pre, W_suc, WH);
    init_x<<<ixBlocks, blk, 0, stream>>>(lane, X, Xh);
    hipMemsetAsync(counts, 0, NROWS * sizeof(int), stream);
    count_kernel<<<dim3(NB, 12), blk, 0, stream>>>(pidx, sidx, counts);
    scan1_kernel<<<NB, blk, 0, stream>>>(counts, offsets, bsum);
    scan2_kernel<<<1, blk, 0, stream>>>(bsum, bpre);
    scan3_kernel<<<NB, blk, 0, stream>>>(offsets, bpre, cursor);
    fill_kernel<<<dim3(NB, 12), blk, 0, stream>>>(pidx, sidx, nhp, nhs,
                                                  cursor, entries);

    for (int i = 0; i < ROUNDS; ++i) {
        // YC = x @ W_ctr[i].T
        {
            const int nwg = 391 * 2;
            gemm_p<<<dim3(nwg), blk, 0, stream>>>(Xh, WH, 48 + i, 1, YC, nwg);
        }
        // 12 message GEMMs + combine (last chunk fuses GN+ReLU -> Hh)
        for (int c0 = 0; c0 < 12; c0 += CH) {
            const int nz = (12 - c0 < CH) ? (12 - c0) : CH;
            const int nwg = 391 * 2 * nz;
            gemm_p<<<dim3(nwg), blk, 0, stream>>>(Xh, WH, i * 12 + c0, nz, YBUF, nwg);
            const bool first = (c0 == 0);
            const bool last  = (c0 + nz >= 12);
            if (first && last)
                combine_f16<1, 1><<<gnBlocks, blk, 0, stream>>>(YC, T16, YBUF,
                    offsets, entries, c0, nz, norm_w + i * DIM, norm_b + i * DIM, Hh);
            else if (first)
                combine_f16<1, 0><<<gnBlocks, blk, 0, stream>>>(YC, T16, YBUF,
                    offsets, entries, c0, nz, norm_w + i * DIM, norm_b + i * DIM, Hh);
            else if (last)
                combine_f16<0, 1><<<gnBlocks, blk, 0, stream>>>(YC, T16, YBUF,
                    offsets, entries, c0, nz, norm_w + i * DIM, norm_b + i * DIM, Hh);
            else
                combine_f16<0, 0><<<gnBlocks, blk, 0, stream>>>(YC, T16, YBUF,
                    offsets, entries, c0, nz, norm_w + i * DIM, norm_b + i * DIM, Hh);
        }
        // y = h @ W_ctr2[i].T
        {
            const int nwg = 391 * 2;
            gemm_p<<<dim3(nwg), blk, 0, stream>>>(Hh, WH, 52 + i, 1, Y2, nwg);
        }
        // x = relu(gn(y) + x)
        gn1_kernel<<<gnBlocks, blk, 0, stream>>>(Y2, c2w + i * DIM,
                                                 c2b + i * DIM, X, Xh);
    }
}

// Round 8
// 1357.831 us; speedup vs baseline: 1.2619x; 1.2619x over previous
//
#include <hip/hip_runtime.h>

#define NROWS 50000
#define DIM   256
#define SHOPS 6
#define ROUNDS 4
#define EPSV  1e-5f
#define ND ((size_t)NROWS * DIM)
#define NB  196                              // ceil(NROWS/256)

typedef _Float16 f16x8 __attribute__((ext_vector_type(8)));
typedef _Float16 f16x4 __attribute__((ext_vector_type(4)));
typedef float    f32x4 __attribute__((ext_vector_type(4)));

#define GLDS16(GP, LP) \
    __builtin_amdgcn_global_load_lds((const __attribute__((address_space(1))) unsigned*)(GP), \
                                     (__attribute__((address_space(3))) unsigned*)(LP), 16, 0, 0)

__device__ __forceinline__ int imin(int a, int b) { return a < b ? a : b; }

// ---------------------------------------------------------------------------
// Pipelined fp16 MFMA GEMM: C[z] = A @ W[wslot(z)]^T, wslot(z) = z==0 ? s0 : s1+z.
// (lets one dispatch cover ctr slot + consecutive msg slots.)
// R6 pipeline: XCD-chunked bijective swizzle, 3-buf counted-vmcnt, 64B-row
// XOR LDS swizzle. NEW: epilogue transposes the 128x128 fp16 tile through
// LDS ([128][136] pad) and writes 8 x 16B coalesced stores per thread
// (full 128B lines) instead of 64 scalar 2B stores.
// ---------------------------------------------------------------------------
__global__ __launch_bounds__(256)
void gemm_p(const _Float16* __restrict__ A, const _Float16* __restrict__ WH,
            int s0, int s1, int nz, _Float16* __restrict__ C16, int nwg)
{
    __shared__ _Float16 lds[3][8192];        // 48KB: pipeline bufs, then epilogue tile
    char* ldsb = (char*)lds;

    // bijective XCD chunking (m204): consecutive g on same XCD; g is bx-major.
    const int bid = blockIdx.x;
    const int q   = nwg >> 3, r = nwg & 7;
    const int xcd = bid & 7,  ii = bid >> 3;
    const int g   = (xcd < r) ? xcd * (q + 1) + ii
                              : r * (q + 1) + (xcd - r) * q + ii;
    const int bx  = g / (2 * nz);
    const int sub = g - bx * 2 * nz;
    const int by  = sub & 1;
    const size_t z = sub >> 1;

    const int tid = threadIdx.x;
    const int l   = tid & 63;
    const int w   = tid >> 6;
    const int wm  = w & 1;
    const int wn  = w >> 1;
    const int bm0 = bx * 128;
    const int bn0 = by * 128;
    const int lr  = l & 15;
    const int sl  = l >> 4;                  // logical 16B k-slot 0..3

    const int wslot = (z == 0) ? s0 : s1 + (int)z;
    const char* Ab = (const char*)A;
    const char* Wb = (const char*)(WH + (size_t)wslot * (DIM * DIM));

    f32x4 acc[4][4];
    #pragma unroll
    for (int mt = 0; mt < 4; ++mt)
        #pragma unroll
        for (int nt = 0; nt < 4; ++nt)
            acc[mt][nt] = (f32x4){0.f, 0.f, 0.f, 0.f};

    // stage k-step `step` (32 k-elems = 64B per row) into buffer `buf`.
    auto stage = [&](int step, int buf) {
        const int kt64 = step * 64;
        char* base = ldsb + buf * 16384;
        #pragma unroll
        for (int qq = 0; qq < 2; ++qq) {
            const int c    = (w * 2 + qq) * 64 + l;   // 16B chunk 0..511
            const int row  = c >> 2;                  // 0..127
            const int slog = (c & 3) ^ ((row >> 1) & 3);
            const int ar   = imin(bm0 + row, NROWS - 1);
            GLDS16(Ab + (size_t)ar * 512 + kt64 + slog * 16,
                   base + (w * 2 + qq) * 1024);
            GLDS16(Wb + (size_t)(bn0 + row) * 512 + kt64 + slog * 16,
                   base + 8192 + (w * 2 + qq) * 1024);
        }
    };

    auto compute = [&](int buf) {
        const char* base = ldsb + buf * 16384;
        f16x8 af[4], bf[4];
        #pragma unroll
        for (int mt = 0; mt < 4; ++mt) {
            const int row = wm * 64 + mt * 16 + lr;
            af[mt] = *(const f16x8*)(base + row * 64 + ((sl ^ ((row >> 1) & 3)) << 4));
        }
        #pragma unroll
        for (int nt = 0; nt < 4; ++nt) {
            const int row = wn * 64 + nt * 16 + lr;
            bf[nt] = *(const f16x8*)(base + 8192 + row * 64 + ((sl ^ ((row >> 1) & 3)) << 4));
        }
        #pragma unroll
        for (int mt = 0; mt < 4; ++mt)
            #pragma unroll
            for (int nt = 0; nt < 4; ++nt)
                acc[mt][nt] = __builtin_amdgcn_mfma_f32_16x16x32_f16(
                    af[mt], bf[nt], acc[mt][nt], 0, 0, 0);
    };

    stage(0, 0);
    stage(1, 1);

    #pragma unroll
    for (int t = 0; t < 7; ++t) {
        asm volatile("s_waitcnt vmcnt(4)" ::: "memory");   // stage(t) landed
        __builtin_amdgcn_s_barrier();                       // all waves ready
        __builtin_amdgcn_sched_barrier(0);                  // pin order
        if (t < 6) stage(t + 2, (t + 2) % 3);               // stays in flight
        compute(t % 3);
    }
    asm volatile("s_waitcnt vmcnt(0)" ::: "memory");        // last stage
    __builtin_amdgcn_s_barrier();
    __builtin_amdgcn_sched_barrier(0);
    compute(7 % 3);

    // ---- epilogue: transpose through LDS, 16B coalesced stores ----
    __syncthreads();                          // pipeline bufs now free
    _Float16* et = (_Float16*)ldsb;           // [128][136] fp16 = 34816 B
    #pragma unroll
    for (int mt = 0; mt < 4; ++mt)
        #pragma unroll
        for (int nt = 0; nt < 4; ++nt)
            #pragma unroll
            for (int j = 0; j < 4; ++j) {
                const int row = wm * 64 + mt * 16 + sl * 4 + j;   // 0..127
                const int col = wn * 64 + nt * 16 + lr;           // 0..127
                et[row * 136 + col] = (_Float16)acc[mt][nt][j];
            }
    __syncthreads();
    #pragma unroll
    for (int qq = 0; qq < 8; ++qq) {
        const int c   = qq * 256 + tid;       // 0..2047 16B-chunk id
        const int row = c >> 4;               // 0..127
        const int cc  = (c & 15) * 8;         // f16 col 0..120
        const int orow = bm0 + row;
        if (orow < NROWS) {
            const f16x8 v = *(const f16x8*)(et + row * 136 + cc);
            *(f16x8*)(C16 + z * ND + (size_t)orow * DIM + bn0 + cc) = v;
        }
    }
}

// ---------------------------------------------------------------------------
__global__ __launch_bounds__(256)
void convert_w(const float* __restrict__ Wctr, const float* __restrict__ Wctr2,
               const float* __restrict__ Wpre, const float* __restrict__ Wsuc,
               _Float16* __restrict__ WH)
{
    const size_t i4 = (size_t)blockIdx.x * 256 + threadIdx.x;
    const size_t NT = (size_t)56 * DIM * DIM / 4;
    if (i4 >= NT) return;
    const size_t e = i4 * 4;
    const int slot = (int)(e >> 16);
    const int off  = (int)(e & 65535);
    const float* src;
    if (slot < 48) {
        const int r = slot / 12, s = slot % 12, k = s >> 1, dir = s & 1;
        src = (dir ? Wsuc : Wpre) + (((size_t)r * SHOPS + k) << 16) + off;
    } else if (slot < 52) {
        src = Wctr + ((size_t)(slot - 48) << 16) + off;
    } else {
        src = Wctr2 + ((size_t)(slot - 52) << 16) + off;
    }
    const float4 v = *(const float4*)src;
    f16x4 h;
    h[0] = (_Float16)v.x; h[1] = (_Float16)v.y;
    h[2] = (_Float16)v.z; h[3] = (_Float16)v.w;
    *(f16x4*)(WH + e) = h;
}

__global__ __launch_bounds__(256)
void init_x(const float* __restrict__ lane, float* __restrict__ X,
            _Float16* __restrict__ Xh)
{
    const size_t i4 = (size_t)blockIdx.x * 256 + threadIdx.x;
    if (i4 >= ND / 4) return;
    const float4 v = *(const float4*)(lane + i4 * 4);
    *(float4*)(X + i4 * 4) = v;
    f16x4 h;
    h[0] = (_Float16)v.x; h[1] = (_Float16)v.y;
    h[2] = (_Float16)v.z; h[3] = (_Float16)v.w;
    *(f16x4*)(Xh + i4 * 4) = h;
}

// x = relu(gn(y)*w+b + res) -> X fp32 + Xh fp16
__global__ __launch_bounds__(256)
void gn1_kernel(const _Float16* __restrict__ inh, const float* __restrict__ w,
                const float* __restrict__ b, float* __restrict__ X,
                _Float16* __restrict__ Xh)
{
    const int lane = threadIdx.x & 63;
    const int wv   = threadIdx.x >> 6;
    const int row  = blockIdx.x * 4 + wv;
    if (row >= NROWS) return;

    const f16x4 hv = *(const f16x4*)(inh + (size_t)row * DIM + lane * 4);
    float4 v;
    v.x = (float)hv[0]; v.y = (float)hv[1]; v.z = (float)hv[2]; v.w = (float)hv[3];
    float s  = v.x + v.y + v.z + v.w;
    float ss = v.x * v.x + v.y * v.y + v.z * v.z + v.w * v.w;
    #pragma unroll
    for (int off = 32; off >= 1; off >>= 1) {
        s  += __shfl_xor(s, off);
        ss += __shfl_xor(ss, off);
    }
    const float m   = s * (1.0f / DIM);
    const float var = ss * (1.0f / DIM) - m * m;
    const float inv = rsqrtf(var + EPSV);

    const float4 wv4 = *(const float4*)(w + lane * 4);
    const float4 bv4 = *(const float4*)(b + lane * 4);
    const float4 r4  = *(const float4*)(X + (size_t)row * DIM + lane * 4);
    float4 o;
    o.x = fmaxf((v.x - m) * inv * wv4.x + bv4.x + r4.x, 0.f);
    o.y = fmaxf((v.y - m) * inv * wv4.y + bv4.y + r4.y, 0.f);
    o.z = fmaxf((v.z - m) * inv * wv4.z + bv4.z + r4.z, 0.f);
    o.w = fmaxf((v.w - m) * inv * wv4.w + bv4.w + r4.w, 0.f);
    *(float4*)(X + (size_t)row * DIM + lane * 4) = o;
    f16x4 oh;
    oh[0] = (_Float16)o.x; oh[1] = (_Float16)o.y;
    oh[2] = (_Float16)o.z; oh[3] = (_Float16)o.w;
    *(f16x4*)(Xh + (size_t)row * DIM + lane * 4) = oh;
}

// ---------------------------------------------------------------------------
// CSR inversion (once per launch; indices constant across rounds)
// ---------------------------------------------------------------------------
__global__ __launch_bounds__(256)
void count_kernel(const int* __restrict__ pidx, const int* __restrict__ sidx,
                  int* __restrict__ counts)
{
    const int i = blockIdx.x * 256 + threadIdx.x;
    if (i >= NROWS) return;
    const int s = blockIdx.y;
    const int k = s >> 1, dir = s & 1;
    const int* scp = (dir ? pidx : sidx) + k * NROWS;
    atomicAdd(&counts[scp[i]], 1);
}

__global__ __launch_bounds__(256)
void scan1_kernel(const int* __restrict__ counts, int* __restrict__ offs,
                  int* __restrict__ bsum)
{
    __shared__ int wsum[4];
    const int tid = threadIdx.x, lane = tid & 63, wv = tid >> 6;
    const int i = blockIdx.x * 256 + tid;
    const int c = (i < NROWS) ? counts[i] : 0;
    int v = c;
    #pragma unroll
    for (int off = 1; off < 64; off <<= 1) {
        const int t = __shfl_up(v, off);
        if (lane >= off) v += t;
    }
    if (lane == 63) wsum[wv] = v;
    __syncthreads();
    int add = 0;
    for (int w = 0; w < wv; ++w) add += wsum[w];
    if (i < NROWS) offs[i] = add + v - c;
    if (tid == 255) bsum[blockIdx.x] = wsum[0] + wsum[1] + wsum[2] + wsum[3];
}

__global__ __launch_bounds__(256)
void scan2_kernel(const int* __restrict__ bsum, int* __restrict__ bpre)
{
    __shared__ int wsum[4];
    const int tid = threadIdx.x, lane = tid & 63, wv = tid >> 6;
    const int c = (tid < NB) ? bsum[tid] : 0;
    int v = c;
    #pragma unroll
    for (int off = 1; off < 64; off <<= 1) {
        const int t = __shfl_up(v, off);
        if (lane >= off) v += t;
    }
    if (lane == 63) wsum[wv] = v;
    __syncthreads();
    int add = 0;
    for (int w = 0; w < wv; ++w) add += wsum[w];
    if (tid < NB) bpre[tid] = add + v - c;
}

__global__ __launch_bounds__(256)
void scan3_kernel(int* __restrict__ offs, const int* __restrict__ bpre,
                  int* __restrict__ cursor)
{
    const int i = blockIdx.x * 256 + threadIdx.x;
    if (i < NROWS) {
        const int v = offs[i] + bpre[blockIdx.x];
        offs[i] = v;
        cursor[i] = v;
    }
    if (i == 0) offs[NROWS] = 12 * NROWS;
}

__global__ __launch_bounds__(256)
void fill_kernel(const int* __restrict__ pidx, const int* __restrict__ sidx,
                 const int* __restrict__ nhp, const int* __restrict__ nhs,
                 int* __restrict__ cursor, int* __restrict__ entries)
{
    const int i = blockIdx.x * 256 + threadIdx.x;
    if (i >= NROWS) return;
    const int s = blockIdx.y;
    const int k = s >> 1, dir = s & 1;
    const int* scp = (dir ? pidx : sidx) + k * NROWS;
    const int* gp  = (dir ? nhs  : nhp)  + k * NROWS;
    const int pos = atomicAdd(&cursor[scp[i]], 1);
    entries[pos] = (s << 16) | gp[i];
}

// ---------------------------------------------------------------------------
// combine: acc = (FIRST ? YC[r] : TEMP16[r]) + sum of Y rows for entries with
// seg in [c0, c0+nch). LAST: fused GroupNorm+ReLU -> Hh. else -> TEMP16.
// ---------------------------------------------------------------------------
template<int FIRST, int LAST>
__global__ __launch_bounds__(256)
void combine_f16(const _Float16* __restrict__ YC, _Float16* __restrict__ TEMP16,
                 const _Float16* __restrict__ YB,
                 const int* __restrict__ offsets, const int* __restrict__ entries,
                 int c0, int nch,
                 const float* __restrict__ gw, const float* __restrict__ gb,
                 _Float16* __restrict__ Hh)
{
    const int lane = threadIdx.x & 63;
    const int wv   = threadIdx.x >> 6;
    const int r    = blockIdx.x * 4 + wv;
    if (r >= NROWS) return;
    const size_t rowoff = (size_t)r * DIM + lane * 4;

    const f16x4 iv = FIRST ? *(const f16x4*)(YC + rowoff)
                           : *(const f16x4*)(TEMP16 + rowoff);
    float4 acc;
    acc.x = (float)iv[0]; acc.y = (float)iv[1];
    acc.z = (float)iv[2]; acc.w = (float)iv[3];

    const int e0 = offsets[r], e1 = offsets[r + 1];
    for (int e = e0; e < e1; ++e) {
        const int ent = entries[e];
        const int s = ent >> 16;
        if ((unsigned)(s - c0) < (unsigned)nch) {
            const f16x4 yv = *(const f16x4*)(YB + (size_t)(s - c0) * ND
                                             + (size_t)(ent & 0xFFFF) * DIM + lane * 4);
            acc.x += (float)yv[0]; acc.y += (float)yv[1];
            acc.z += (float)yv[2]; acc.w += (float)yv[3];
        }
    }

    if (LAST) {
        float s  = acc.x + acc.y + acc.z + acc.w;
        float ss = acc.x * acc.x + acc.y * acc.y + acc.z * acc.z + acc.w * acc.w;
        #pragma unroll
        for (int off = 32; off >= 1; off >>= 1) {
            s  += __shfl_xor(s, off);
            ss += __shfl_xor(ss, off);
        }
        const float m   = s * (1.0f / DIM);
        const float var = ss * (1.0f / DIM) - m * m;
        const float inv = rsqrtf(var + EPSV);
        const float4 wv4 = *(const float4*)(gw + lane * 4);
        const float4 bv4 = *(const float4*)(gb + lane * 4);
        f16x4 o;
        o[0] = (_Float16)fmaxf((acc.x - m) * inv * wv4.x + bv4.x, 0.f);
        o[1] = (_Float16)fmaxf((acc.y - m) * inv * wv4.y + bv4.y, 0.f);
        o[2] = (_Float16)fmaxf((acc.z - m) * inv * wv4.z + bv4.z, 0.f);
        o[3] = (_Float16)fmaxf((acc.w - m) * inv * wv4.w + bv4.w, 0.f);
        *(f16x4*)(Hh + rowoff) = o;
    } else {
        f16x4 o;
        o[0] = (_Float16)acc.x; o[1] = (_Float16)acc.y;
        o[2] = (_Float16)acc.z; o[3] = (_Float16)acc.w;
        *(f16x4*)(TEMP16 + rowoff) = o;
    }
}

// ---------------------------------------------------------------------------
extern "C" void kernel_launch(void* const* d_in, const int* in_sizes, int n_in,
                              void* d_out, int out_size, void* d_ws, size_t ws_size,
                              hipStream_t stream)
{
    const float* lane   = (const float*)d_in[0];
    const float* W_ctr  = (const float*)d_in[1];
    const float* norm_w = (const float*)d_in[2];
    const float* norm_b = (const float*)d_in[3];
    const float* W_ctr2 = (const float*)d_in[4];
    const float* c2w    = (const float*)d_in[5];
    const float* c2b    = (const float*)d_in[6];
    const float* W_pre  = (const float*)d_in[7];
    const float* W_suc  = (const float*)d_in[8];
    const int*   pidx   = (const int*)d_in[9];
    const int*   sidx   = (const int*)d_in[10];
    const int*   nhp    = (const int*)d_in[11];
    const int*   nhs    = (const int*)d_in[12];

    float* X = (float*)d_out;

    // ---- workspace layout (YC must immediately precede YBUF) ----
    char* p = (char*)d_ws;
    int* counts  = (int*)p; p += (size_t)NROWS * 4;
    int* offsets = (int*)p; p += (size_t)(NROWS + 4) * 4;
    int* cursor  = (int*)p; p += (size_t)NROWS * 4;
    int* bsum    = (int*)p; p += 256 * 4;
    int* bpre    = (int*)p; p += 256 * 4;
    int* entries = (int*)p; p += (size_t)12 * NROWS * 4;
    p = (char*)(((uintptr_t)p + 15) & ~(uintptr_t)15);
    _Float16* Xh   = (_Float16*)p; p += ND * 2;
    _Float16* Hh   = (_Float16*)p; p += ND * 2;
    _Float16* T16  = (_Float16*)p; p += ND * 2;
    _Float16* WH   = (_Float16*)p; p += (size_t)56 * DIM * DIM * 2;
    p = (char*)(((uintptr_t)p + 15) & ~(uintptr_t)15);
    _Float16* YC   = (_Float16*)p; p += ND * 2;
    _Float16* YBUF = (_Float16*)p;            // contiguous after YC

    const size_t used = (size_t)(p - (char*)d_ws);
    int nslot = (int)((ws_size - used) / (ND * 2));
    if (nslot < 1) nslot = 1;
    int CH = nslot > 12 ? 12 : nslot;
    const int nchunks = (12 + CH - 1) / CH;
    CH = (12 + nchunks - 1) / nchunks;        // ws history guarantees CH=6
    _Float16* Y2 = YBUF;                      // ctr2 output reuses slot 0

    const dim3 blk(256);
    const int  gnBlocks = (NROWS + 3) / 4;
    const int  cwBlocks = (int)(((size_t)56 * DIM * DIM / 4 + 255) / 256);
    const int  ixBlocks = (int)((ND / 4 + 255) / 256);

    // one-time prep
    convert_w<<<cwBlocks, blk, 0, stream>>>(W_ctr, W_ctr2, W_pre, W_suc, WH);
    init_x<<<ixBlocks, blk, 0, stream>>>(lane, X, Xh);
    hipMemsetAsync(counts, 0, NROWS * sizeof(int), stream);
    count_kernel<<<dim3(NB, 12), blk, 0, stream>>>(pidx, sidx, counts);
    scan1_kernel<<<NB, blk, 0, stream>>>(counts, offsets, bsum);
    scan2_kernel<<<1, blk, 0, stream>>>(bsum, bpre);
    scan3_kernel<<<NB, blk, 0, stream>>>(offsets, bpre, cursor);
    fill_kernel<<<dim3(NB, 12), blk, 0, stream>>>(pidx, sidx, nhp, nhs,
                                                  cursor, entries);

    for (int i = 0; i < ROUNDS; ++i) {
        // chunked msg GEMMs; first chunk also carries the ctr GEMM as z=0
        for (int c0 = 0; c0 < 12; c0 += CH) {
            const int nz  = (12 - c0 < CH) ? (12 - c0) : CH;
            const bool first = (c0 == 0);
            const bool last  = (c0 + nz >= 12);
            if (first) {
                // z=0 -> ctr (slot 48+i) -> YC; z=1..nz -> msg c0..c0+nz-1 -> YBUF
                const int nwg = 391 * 2 * (nz + 1);
                gemm_p<<<dim3(nwg), blk, 0, stream>>>(Xh, WH, 48 + i,
                                                      i * 12 + c0 - 1, nz + 1, YC, nwg);
            } else {
                const int nwg = 391 * 2 * nz;
                gemm_p<<<dim3(nwg), blk, 0, stream>>>(Xh, WH, i * 12 + c0,
                                                      i * 12 + c0, nz, YBUF, nwg);
            }
            if (first && last)
                combine_f16<1, 1><<<gnBlocks, blk, 0, stream>>>(YC, T16, YBUF,
                    offsets, entries, c0, nz, norm_w + i * DIM, norm_b + i * DIM, Hh);
            else if (first)
                combine_f16<1, 0><<<gnBlocks, blk, 0, stream>>>(YC, T16, YBUF,
                    offsets, entries, c0, nz, norm_w + i * DIM, norm_b + i * DIM, Hh);
            else if (last)
                combine_f16<0, 1><<<gnBlocks, blk, 0, stream>>>(YC, T16, YBUF,
                    offsets, entries, c0, nz, norm_w + i * DIM, norm_b + i * DIM, Hh);
            else
                combine_f16<0, 0><<<gnBlocks, blk, 0, stream>>>(YC, T16, YBUF,
                    offsets, entries, c0, nz, norm_w + i * DIM, norm_b + i * DIM, Hh);
        }
        // y = h @ W_ctr2[i].T
        {
            const int nwg = 391 * 2;
            gemm_p<<<dim3(nwg), blk, 0, stream>>>(Hh, WH, 52 + i, 52 + i, 1, Y2, nwg);
        }
        // x = relu(gn(y) + x)
        gn1_kernel<<<gnBlocks, blk, 0, stream>>>(Y2, c2w + i * DIM,
                                                 c2b + i * DIM, X, Xh);
    }
}

// Round 9
// 1304.557 us; speedup vs baseline: 1.3134x; 1.0408x over previous
//
#include <hip/hip_runtime.h>

#define NROWS 50000
#define DIM   256
#define SHOPS 6
#define ROUNDS 4
#define EPSV  1e-5f
#define ND ((size_t)NROWS * DIM)
#define NB  196                              // ceil(NROWS/256)

typedef _Float16 f16x8 __attribute__((ext_vector_type(8)));
typedef _Float16 f16x4 __attribute__((ext_vector_type(4)));
typedef float    f32x4 __attribute__((ext_vector_type(4)));

#define GLDS16(GP, LP) \
    __builtin_amdgcn_global_load_lds((const __attribute__((address_space(1))) unsigned*)(GP), \
                                     (__attribute__((address_space(3))) unsigned*)(LP), 16, 0, 0)

__device__ __forceinline__ int imin(int a, int b) { return a < b ? a : b; }

// ---------------------------------------------------------------------------
// Pipelined fp16 MFMA GEMM: C[z] = A @ W[wslot(z)]^T, wslot(z)= z==0 ? s0 : s1+z.
// R8 structure (XCD-chunked bijective swizzle, 64B-row XOR LDS swizzle,
// LDS-transposed coalesced epilogue, ctr merged as z=0) with TWO changes:
//  - 2-buffer pipeline, 32KB LDS total -> 5 blocks/CU cap (was 3 at 48KB).
//    Per k-step: vmcnt(0); s_barrier; stage(t+1); compute(t).
//  - epilogue transposes in two 64x136 half-tiles (fits 32KB).
// ---------------------------------------------------------------------------
__global__ __launch_bounds__(256)
void gemm_p(const _Float16* __restrict__ A, const _Float16* __restrict__ WH,
            int s0, int s1, int nz, _Float16* __restrict__ C16, int nwg)
{
    __shared__ _Float16 lds[2][8192];        // 2 x 16KB (A 8KB + W 8KB each)
    char* ldsb = (char*)lds;

    // bijective XCD chunking (m204): consecutive g on same XCD; g is bx-major.
    const int bid = blockIdx.x;
    const int q   = nwg >> 3, r = nwg & 7;
    const int xcd = bid & 7,  ii = bid >> 3;
    const int g   = (xcd < r) ? xcd * (q + 1) + ii
                              : r * (q + 1) + (xcd - r) * q + ii;
    const int bx  = g / (2 * nz);
    const int sub = g - bx * 2 * nz;
    const int by  = sub & 1;
    const size_t z = sub >> 1;

    const int tid = threadIdx.x;
    const int l   = tid & 63;
    const int w   = tid >> 6;
    const int wm  = w & 1;
    const int wn  = w >> 1;
    const int bm0 = bx * 128;
    const int bn0 = by * 128;
    const int lr  = l & 15;
    const int sl  = l >> 4;                  // logical 16B k-slot 0..3

    const int wslot = (z == 0) ? s0 : s1 + (int)z;
    const char* Ab = (const char*)A;
    const char* Wb = (const char*)(WH + (size_t)wslot * (DIM * DIM));

    f32x4 acc[4][4];
    #pragma unroll
    for (int mt = 0; mt < 4; ++mt)
        #pragma unroll
        for (int nt = 0; nt < 4; ++nt)
            acc[mt][nt] = (f32x4){0.f, 0.f, 0.f, 0.f};

    // stage k-step `step` (32 k-elems = 64B per row) into buffer `buf`.
    auto stage = [&](int step, int buf) {
        const int kt64 = step * 64;
        char* base = ldsb + buf * 16384;
        #pragma unroll
        for (int qq = 0; qq < 2; ++qq) {
            const int c    = (w * 2 + qq) * 64 + l;   // 16B chunk 0..511
            const int row  = c >> 2;                  // 0..127
            const int slog = (c & 3) ^ ((row >> 1) & 3);
            const int ar   = imin(bm0 + row, NROWS - 1);
            GLDS16(Ab + (size_t)ar * 512 + kt64 + slog * 16,
                   base + (w * 2 + qq) * 1024);
            GLDS16(Wb + (size_t)(bn0 + row) * 512 + kt64 + slog * 16,
                   base + 8192 + (w * 2 + qq) * 1024);
        }
    };

    auto compute = [&](int buf) {
        const char* base = ldsb + buf * 16384;
        f16x8 af[4], bf[4];
        #pragma unroll
        for (int mt = 0; mt < 4; ++mt) {
            const int row = wm * 64 + mt * 16 + lr;
            af[mt] = *(const f16x8*)(base + row * 64 + ((sl ^ ((row >> 1) & 3)) << 4));
        }
        #pragma unroll
        for (int nt = 0; nt < 4; ++nt) {
            const int row = wn * 64 + nt * 16 + lr;
            bf[nt] = *(const f16x8*)(base + 8192 + row * 64 + ((sl ^ ((row >> 1) & 3)) << 4));
        }
        #pragma unroll
        for (int mt = 0; mt < 4; ++mt)
            #pragma unroll
            for (int nt = 0; nt < 4; ++nt)
                acc[mt][nt] = __builtin_amdgcn_mfma_f32_16x16x32_f16(
                    af[mt], bf[nt], acc[mt][nt], 0, 0, 0);
    };

    stage(0, 0);

    #pragma unroll
    for (int t = 0; t < 8; ++t) {
        asm volatile("s_waitcnt vmcnt(0)" ::: "memory");   // my stage(t) landed
        __builtin_amdgcn_s_barrier();                       // all landed; prev compute done
        __builtin_amdgcn_sched_barrier(0);                  // pin order
        if (t < 7) stage(t + 1, (t + 1) & 1);               // flies under compute(t)
        compute(t & 1);
    }

    // ---- epilogue: two 64x136 half-tiles through LDS, 16B coalesced stores ----
    _Float16* et = (_Float16*)ldsb;           // [64][136] fp16 = 17408 B
    const size_t zoff = z * ND;
    #pragma unroll
    for (int half = 0; half < 2; ++half) {
        __syncthreads();
        if (wm == half) {
            #pragma unroll
            for (int mt = 0; mt < 4; ++mt)
                #pragma unroll
                for (int nt = 0; nt < 4; ++nt)
                    #pragma unroll
                    for (int j = 0; j < 4; ++j) {
                        const int row = mt * 16 + sl * 4 + j;   // 0..63
                        const int col = wn * 64 + nt * 16 + lr; // 0..127
                        et[row * 136 + col] = (_Float16)acc[mt][nt][j];
                    }
        }
        __syncthreads();
        #pragma unroll
        for (int qq = 0; qq < 4; ++qq) {
            const int c    = qq * 256 + tid;  // 0..1023 16B-chunk id
            const int row  = c >> 4;          // 0..63
            const int cc   = (c & 15) * 8;    // f16 col 0..120
            const int orow = bm0 + half * 64 + row;
            if (orow < NROWS) {
                const f16x8 v = *(const f16x8*)(et + row * 136 + cc);
                *(f16x8*)(C16 + zoff + (size_t)orow * DIM + bn0 + cc) = v;
            }
        }
    }
}

// ---------------------------------------------------------------------------
__global__ __launch_bounds__(256)
void convert_w(const float* __restrict__ Wctr, const float* __restrict__ Wctr2,
               const float* __restrict__ Wpre, const float* __restrict__ Wsuc,
               _Float16* __restrict__ WH)
{
    const size_t i4 = (size_t)blockIdx.x * 256 + threadIdx.x;
    const size_t NT = (size_t)56 * DIM * DIM / 4;
    if (i4 >= NT) return;
    const size_t e = i4 * 4;
    const int slot = (int)(e >> 16);
    const int off  = (int)(e & 65535);
    const float* src;
    if (slot < 48) {
        const int r = slot / 12, s = slot % 12, k = s >> 1, dir = s & 1;
        src = (dir ? Wsuc : Wpre) + (((size_t)r * SHOPS + k) << 16) + off;
    } else if (slot < 52) {
        src = Wctr + ((size_t)(slot - 48) << 16) + off;
    } else {
        src = Wctr2 + ((size_t)(slot - 52) << 16) + off;
    }
    const float4 v = *(const float4*)src;
    f16x4 h;
    h[0] = (_Float16)v.x; h[1] = (_Float16)v.y;
    h[2] = (_Float16)v.z; h[3] = (_Float16)v.w;
    *(f16x4*)(WH + e) = h;
}

// Xh = fp16(lane). fp32 X is NOT materialized until the final round's gn1.
__global__ __launch_bounds__(256)
void init_x(const float* __restrict__ lane, _Float16* __restrict__ Xh)
{
    const size_t i4 = (size_t)blockIdx.x * 256 + threadIdx.x;
    if (i4 >= ND / 4) return;
    const float4 v = *(const float4*)(lane + i4 * 4);
    f16x4 h;
    h[0] = (_Float16)v.x; h[1] = (_Float16)v.y;
    h[2] = (_Float16)v.z; h[3] = (_Float16)v.w;
    *(f16x4*)(Xh + i4 * 4) = h;
}

// x = relu(gn(y)*w+b + res[fp16]) -> Xh fp16 (+ X fp32 iff WRITEX, final round)
template<int WRITEX>
__global__ __launch_bounds__(256)
void gn1_kernel(const _Float16* __restrict__ inh, const float* __restrict__ w,
                const float* __restrict__ b, const _Float16* __restrict__ resh,
                float* __restrict__ X, _Float16* __restrict__ Xh)
{
    const int lane = threadIdx.x & 63;
    const int wv   = threadIdx.x >> 6;
    const int row  = blockIdx.x * 4 + wv;
    if (row >= NROWS) return;
    const size_t rowoff = (size_t)row * DIM + lane * 4;

    const f16x4 hv = *(const f16x4*)(inh + rowoff);
    float4 v;
    v.x = (float)hv[0]; v.y = (float)hv[1]; v.z = (float)hv[2]; v.w = (float)hv[3];
    float s  = v.x + v.y + v.z + v.w;
    float ss = v.x * v.x + v.y * v.y + v.z * v.z + v.w * v.w;
    #pragma unroll
    for (int off = 32; off >= 1; off >>= 1) {
        s  += __shfl_xor(s, off);
        ss += __shfl_xor(ss, off);
    }
    const float m   = s * (1.0f / DIM);
    const float var = ss * (1.0f / DIM) - m * m;
    const float inv = rsqrtf(var + EPSV);

    const float4 wv4 = *(const float4*)(w + lane * 4);
    const float4 bv4 = *(const float4*)(b + lane * 4);
    const f16x4  r4  = *(const f16x4*)(resh + rowoff);
    float4 o;
    o.x = fmaxf((v.x - m) * inv * wv4.x + bv4.x + (float)r4[0], 0.f);
    o.y = fmaxf((v.y - m) * inv * wv4.y + bv4.y + (float)r4[1], 0.f);
    o.z = fmaxf((v.z - m) * inv * wv4.z + bv4.z + (float)r4[2], 0.f);
    o.w = fmaxf((v.w - m) * inv * wv4.w + bv4.w + (float)r4[3], 0.f);
    if (WRITEX)
        *(float4*)(X + rowoff) = o;
    f16x4 oh;
    oh[0] = (_Float16)o.x; oh[1] = (_Float16)o.y;
    oh[2] = (_Float16)o.z; oh[3] = (_Float16)o.w;
    *(f16x4*)(Xh + rowoff) = oh;
}

// ---------------------------------------------------------------------------
// CSR inversion (once per launch; indices constant across rounds)
// ---------------------------------------------------------------------------
__global__ __launch_bounds__(256)
void count_kernel(const int* __restrict__ pidx, const int* __restrict__ sidx,
                  int* __restrict__ counts)
{
    const int i = blockIdx.x * 256 + threadIdx.x;
    if (i >= NROWS) return;
    const int s = blockIdx.y;
    const int k = s >> 1, dir = s & 1;
    const int* scp = (dir ? pidx : sidx) + k * NROWS;
    atomicAdd(&counts[scp[i]], 1);
}

__global__ __launch_bounds__(256)
void scan1_kernel(const int* __restrict__ counts, int* __restrict__ offs,
                  int* __restrict__ bsum)
{
    __shared__ int wsum[4];
    const int tid = threadIdx.x, lane = tid & 63, wv = tid >> 6;
    const int i = blockIdx.x * 256 + tid;
    const int c = (i < NROWS) ? counts[i] : 0;
    int v = c;
    #pragma unroll
    for (int off = 1; off < 64; off <<= 1) {
        const int t = __shfl_up(v, off);
        if (lane >= off) v += t;
    }
    if (lane == 63) wsum[wv] = v;
    __syncthreads();
    int add = 0;
    for (int w = 0; w < wv; ++w) add += wsum[w];
    if (i < NROWS) offs[i] = add + v - c;
    if (tid == 255) bsum[blockIdx.x] = wsum[0] + wsum[1] + wsum[2] + wsum[3];
}

__global__ __launch_bounds__(256)
void scan2_kernel(const int* __restrict__ bsum, int* __restrict__ bpre)
{
    __shared__ int wsum[4];
    const int tid = threadIdx.x, lane = tid & 63, wv = tid >> 6;
    const int c = (tid < NB) ? bsum[tid] : 0;
    int v = c;
    #pragma unroll
    for (int off = 1; off < 64; off <<= 1) {
        const int t = __shfl_up(v, off);
        if (lane >= off) v += t;
    }
    if (lane == 63) wsum[wv] = v;
    __syncthreads();
    int add = 0;
    for (int w = 0; w < wv; ++w) add += wsum[w];
    if (tid < NB) bpre[tid] = add + v - c;
}

__global__ __launch_bounds__(256)
void scan3_kernel(int* __restrict__ offs, const int* __restrict__ bpre,
                  int* __restrict__ cursor)
{
    const int i = blockIdx.x * 256 + threadIdx.x;
    if (i < NROWS) {
        const int v = offs[i] + bpre[blockIdx.x];
        offs[i] = v;
        cursor[i] = v;
    }
    if (i == 0) offs[NROWS] = 12 * NROWS;
}

__global__ __launch_bounds__(256)
void fill_kernel(const int* __restrict__ pidx, const int* __restrict__ sidx,
                 const int* __restrict__ nhp, const int* __restrict__ nhs,
                 int* __restrict__ cursor, int* __restrict__ entries)
{
    const int i = blockIdx.x * 256 + threadIdx.x;
    if (i >= NROWS) return;
    const int s = blockIdx.y;
    const int k = s >> 1, dir = s & 1;
    const int* scp = (dir ? pidx : sidx) + k * NROWS;
    const int* gp  = (dir ? nhs  : nhp)  + k * NROWS;
    const int pos = atomicAdd(&cursor[scp[i]], 1);
    entries[pos] = (s << 16) | gp[i];
}

// ---------------------------------------------------------------------------
// combine: acc = (FIRST ? YC[r] : TEMP16[r]) + sum of Y rows for entries with
// seg in [c0, c0+nch). LAST: fused GroupNorm+ReLU -> Hh. else -> TEMP16.
// ---------------------------------------------------------------------------
template<int FIRST, int LAST>
__global__ __launch_bounds__(256)
void combine_f16(const _Float16* __restrict__ YC, _Float16* __restrict__ TEMP16,
                 const _Float16* __restrict__ YB,
                 const int* __restrict__ offsets, const int* __restrict__ entries,
                 int c0, int nch,
                 const float* __restrict__ gw, const float* __restrict__ gb,
                 _Float16* __restrict__ Hh)
{
    const int lane = threadIdx.x & 63;
    const int wv   = threadIdx.x >> 6;
    const int r    = blockIdx.x * 4 + wv;
    if (r >= NROWS) return;
    const size_t rowoff = (size_t)r * DIM + lane * 4;

    const f16x4 iv = FIRST ? *(const f16x4*)(YC + rowoff)
                           : *(const f16x4*)(TEMP16 + rowoff);
    float4 acc;
    acc.x = (float)iv[0]; acc.y = (float)iv[1];
    acc.z = (float)iv[2]; acc.w = (float)iv[3];

    const int e0 = offsets[r], e1 = offsets[r + 1];
    for (int e = e0; e < e1; ++e) {
        const int ent = entries[e];
        const int s = ent >> 16;
        if ((unsigned)(s - c0) < (unsigned)nch) {
            const f16x4 yv = *(const f16x4*)(YB + (size_t)(s - c0) * ND
                                             + (size_t)(ent & 0xFFFF) * DIM + lane * 4);
            acc.x += (float)yv[0]; acc.y += (float)yv[1];
            acc.z += (float)yv[2]; acc.w += (float)yv[3];
        }
    }

    if (LAST) {
        float s  = acc.x + acc.y + acc.z + acc.w;
        float ss = acc.x * acc.x + acc.y * acc.y + acc.z * acc.z + acc.w * acc.w;
        #pragma unroll
        for (int off = 32; off >= 1; off >>= 1) {
            s  += __shfl_xor(s, off);
            ss += __shfl_xor(ss, off);
        }
        const float m   = s * (1.0f / DIM);
        const float var = ss * (1.0f / DIM) - m * m;
        const float inv = rsqrtf(var + EPSV);
        const float4 wv4 = *(const float4*)(gw + lane * 4);
        const float4 bv4 = *(const float4*)(gb + lane * 4);
        f16x4 o;
        o[0] = (_Float16)fmaxf((acc.x - m) * inv * wv4.x + bv4.x, 0.f);
        o[1] = (_Float16)fmaxf((acc.y - m) * inv * wv4.y + bv4.y, 0.f);
        o[2] = (_Float16)fmaxf((acc.z - m) * inv * wv4.z + bv4.z, 0.f);
        o[3] = (_Float16)fmaxf((acc.w - m) * inv * wv4.w + bv4.w, 0.f);
        *(f16x4*)(Hh + rowoff) = o;
    } else {
        f16x4 o;
        o[0] = (_Float16)acc.x; o[1] = (_Float16)acc.y;
        o[2] = (_Float16)acc.z; o[3] = (_Float16)acc.w;
        *(f16x4*)(TEMP16 + rowoff) = o;
    }
}

// ---------------------------------------------------------------------------
extern "C" void kernel_launch(void* const* d_in, const int* in_sizes, int n_in,
                              void* d_out, int out_size, void* d_ws, size_t ws_size,
                              hipStream_t stream)
{
    const float* lane   = (const float*)d_in[0];
    const float* W_ctr  = (const float*)d_in[1];
    const float* norm_w = (const float*)d_in[2];
    const float* norm_b = (const float*)d_in[3];
    const float* W_ctr2 = (const float*)d_in[4];
    const float* c2w    = (const float*)d_in[5];
    const float* c2b    = (const float*)d_in[6];
    const float* W_pre  = (const float*)d_in[7];
    const float* W_suc  = (const float*)d_in[8];
    const int*   pidx   = (const int*)d_in[9];
    const int*   sidx   = (const int*)d_in[10];
    const int*   nhp    = (const int*)d_in[11];
    const int*   nhs    = (const int*)d_in[12];

    float* X = (float*)d_out;

    // ---- workspace layout (YC must immediately precede YBUF) ----
    char* p = (char*)d_ws;
    int* counts  = (int*)p; p += (size_t)NROWS * 4;
    int* offsets = (int*)p; p += (size_t)(NROWS + 4) * 4;
    int* cursor  = (int*)p; p += (size_t)NROWS * 4;
    int* bsum    = (int*)p; p += 256 * 4;
    int* bpre    = (int*)p; p += 256 * 4;
    int* entries = (int*)p; p += (size_t)12 * NROWS * 4;
    p = (char*)(((uintptr_t)p + 15) & ~(uintptr_t)15);
    _Float16* Xh   = (_Float16*)p; p += ND * 2;
    _Float16* Hh   = (_Float16*)p; p += ND * 2;
    _Float16* T16  = (_Float16*)p; p += ND * 2;
    _Float16* WH   = (_Float16*)p; p += (size_t)56 * DIM * DIM * 2;
    p = (char*)(((uintptr_t)p + 15) & ~(uintptr_t)15);
    _Float16* YC   = (_Float16*)p; p += ND * 2;
    _Float16* YBUF = (_Float16*)p;            // contiguous after YC

    const size_t used = (size_t)(p - (char*)d_ws);
    int nslot = (int)((ws_size - used) / (ND * 2));
    if (nslot < 1) nslot = 1;
    int CH = nslot > 12 ? 12 : nslot;
    const int nchunks = (12 + CH - 1) / CH;
    CH = (12 + nchunks - 1) / nchunks;        // ws history gives CH=6
    _Float16* Y2 = YBUF;                      // ctr2 output reuses slot 0

    const dim3 blk(256);
    const int  gnBlocks = (NROWS + 3) / 4;
    const int  cwBlocks = (int)(((size_t)56 * DIM * DIM / 4 + 255) / 256);
    const int  ixBlocks = (int)((ND / 4 + 255) / 256);

    // one-time prep
    convert_w<<<cwBlocks, blk, 0, stream>>>(W_ctr, W_ctr2, W_pre, W_suc, WH);
    init_x<<<ixBlocks, blk, 0, stream>>>(lane, Xh);
    hipMemsetAsync(counts, 0, NROWS * sizeof(int), stream);
    count_kernel<<<dim3(NB, 12), blk, 0, stream>>>(pidx, sidx, counts);
    scan1_kernel<<<NB, blk, 0, stream>>>(counts, offsets, bsum);
    scan2_kernel<<<1, blk, 0, stream>>>(bsum, bpre);
    scan3_kernel<<<NB, blk, 0, stream>>>(offsets, bpre, cursor);
    fill_kernel<<<dim3(NB, 12), blk, 0, stream>>>(pidx, sidx, nhp, nhs,
                                                  cursor, entries);

    for (int i = 0; i < ROUNDS; ++i) {
        // chunked msg GEMMs; first chunk also carries the ctr GEMM as z=0
        for (int c0 = 0; c0 < 12; c0 += CH) {
            const int nz  = (12 - c0 < CH) ? (12 - c0) : CH;
            const bool first = (c0 == 0);
            const bool last  = (c0 + nz >= 12);
            if (first) {
                // z=0 -> ctr (slot 48+i) -> YC; z=1..nz -> msg c0..c0+nz-1 -> YBUF
                const int nwg = 391 * 2 * (nz + 1);
                gemm_p<<<dim3(nwg), blk, 0, stream>>>(Xh, WH, 48 + i,
                                                      i * 12 + c0 - 1, nz + 1, YC, nwg);
            } else {
                const int nwg = 391 * 2 * nz;
                gemm_p<<<dim3(nwg), blk, 0, stream>>>(Xh, WH, i * 12 + c0,
                                                      i * 12 + c0, nz, YBUF, nwg);
            }
            if (first && last)
                combine_f16<1, 1><<<gnBlocks, blk, 0, stream>>>(YC, T16, YBUF,
                    offsets, entries, c0, nz, norm_w + i * DIM, norm_b + i * DIM, Hh);
            else if (first)
                combine_f16<1, 0><<<gnBlocks, blk, 0, stream>>>(YC, T16, YBUF,
                    offsets, entries, c0, nz, norm_w + i * DIM, norm_b + i * DIM, Hh);
            else if (last)
                combine_f16<0, 1><<<gnBlocks, blk, 0, stream>>>(YC, T16, YBUF,
                    offsets, entries, c0, nz, norm_w + i * DIM, norm_b + i * DIM, Hh);
            else
                combine_f16<0, 0><<<gnBlocks, blk, 0, stream>>>(YC, T16, YBUF,
                    offsets, entries, c0, nz, norm_w + i * DIM, norm_b + i * DIM, Hh);
        }
        // y = h @ W_ctr2[i].T
        {
            const int nwg = 391 * 2;
            gemm_p<<<dim3(nwg), blk, 0, stream>>>(Hh, WH, 52 + i, 52 + i, 1, Y2, nwg);
        }
        // x = relu(gn(y) + x); fp32 X written only in the final round
        if (i == ROUNDS - 1)
            gn1_kernel<1><<<gnBlocks, blk, 0, stream>>>(Y2, c2w + i * DIM,
                                                        c2b + i * DIM, Xh, X, Xh);
        else
            gn1_kernel<0><<<gnBlocks, blk, 0, stream>>>(Y2, c2w + i * DIM,
                                                        c2b + i * DIM, Xh, X, Xh);
    }
}